// Round 2
// baseline (25381.563 us; speedup 1.0000x reference)
//
#include <hip/hip_runtime.h>

// Problem dims
#define TT   512
#define BB   256
#define OBSD 256
#define DD   512
#define HH   512
#define MROWS (TT*BB)   // 131072

typedef __attribute__((ext_vector_type(8))) short short8;
typedef __attribute__((ext_vector_type(4))) float f32x4;

__device__ __forceinline__ ushort f2b(float f){
  unsigned int x = __float_as_uint(f);
  x = (x + 0x7fffu + ((x >> 16) & 1u)) >> 16;   // RNE
  return (ushort)x;
}
__device__ __forceinline__ float b2f(ushort u){
  return __uint_as_float(((unsigned int)u) << 16);
}
__device__ __forceinline__ float sigm(float x){ return 1.f/(1.f + __expf(-x)); }
__device__ __forceinline__ float tanh_f(float x){ return 1.f - 2.f/(__expf(2.f*x) + 1.f); }

// ---------------- transpose f32 [K,N] -> bf16 [N,K] ----------------
__global__ void k_transpose_bf16(const float* __restrict__ W, ushort* __restrict__ Wt,
                                 int K, int N){
  int i = blockIdx.x*256 + threadIdx.x;
  if(i >= K*N) return;
  int k = i / N, n = i % N;
  Wt[(size_t)n*K + k] = f2b(W[i]);
}

// ---------------- detect done dtype (byte-packed vs 4-byte) ----------------
// Reads first 32768 ints = 131072 bytes: safe under both layouts.
// byte-packed bernoulli(0.01): ~1290 nonzero ints; int32 storage: ~328.
__global__ void k_detect(const int* __restrict__ done, int* __restrict__ flag){
  __shared__ int cnt;
  if(threadIdx.x == 0) cnt = 0;
  __syncthreads();
  int c = 0;
  for(int i = threadIdx.x; i < 32768; i += 256) c += (done[i] != 0);
  for(int off = 32; off; off >>= 1) c += __shfl_down(c, off, 64);
  if((threadIdx.x & 63) == 0) atomicAdd(&cnt, c);
  __syncthreads();
  if(threadIdx.x == 0) *flag = (cnt > 700) ? 1 : 0;  // 1 => byte-packed bools
}

// ---------------- generic MFMA GEMM: C[M,N]=op(A[M,K] @ Bt[N,K]^T + bias) ----------------
// A is f32 (a_f32=1) or bf16. Bt row-major [N,K] bf16. C bf16.
// Block: 256 thr = 4 waves; tile 64x64; wave w -> rows [w*16,w*16+16), all 64 cols.
__global__ __launch_bounds__(256) void k_gemm(const void* __restrict__ Av, int a_f32,
                                              const ushort* __restrict__ Bt,
                                              const float* __restrict__ bias,
                                              ushort* __restrict__ C,
                                              int M, int N, int K, int relu){
  const int w = threadIdx.x >> 6, l = threadIdx.x & 63;
  const int l16 = l & 15, l4 = l >> 4;
  const size_t m0 = (size_t)blockIdx.x*64 + w*16;
  const size_t n0 = (size_t)blockIdx.y*64;
  const size_t arow = m0 + l16;
  f32x4 acc[4] = {};
  const ushort* bp[4];
  #pragma unroll
  for(int nt=0; nt<4; nt++) bp[nt] = Bt + (n0 + nt*16 + l16)*(size_t)K;

  for(int k0 = 0; k0 < K; k0 += 32){
    const int kb = k0 + l4*8;
    short8 a;
    if(a_f32){
      const float* A = (const float*)Av + arow*(size_t)K + kb;
      union{ short8 v; ushort u[8]; } t;
      #pragma unroll
      for(int j=0;j<8;j++) t.u[j] = f2b(A[j]);
      a = t.v;
    } else {
      a = *(const short8*)((const ushort*)Av + arow*(size_t)K + kb);
    }
    #pragma unroll
    for(int nt=0; nt<4; nt++){
      const short8 b = *(const short8*)(bp[nt] + kb);
      acc[nt] = __builtin_amdgcn_mfma_f32_16x16x32_bf16(a, b, acc[nt], 0, 0, 0);
    }
  }
  #pragma unroll
  for(int nt=0; nt<4; nt++){
    const int col = (int)n0 + nt*16 + l16;
    const float bv = bias[col];
    #pragma unroll
    for(int r=0; r<4; r++){
      const size_t row = m0 + l4*4 + r;
      float v = acc[nt][r] + bv;
      if(relu) v = fmaxf(v, 0.f);
      C[row*(size_t)N + col] = f2b(v);
    }
  }
}

// ---------------- GRU scan (chunk of `steps` timesteps) ----------------
// 16 blocks x 1024 thr (16 waves). Block owns 16 batch rows; wave w owns d-slice [w*32,w*32+32).
// h kept f32+bf16 in LDS; Wh^T streamed from L2 per step (bf16, direct B-frag loads).
// h carried across chunk kernels via h_in (read) / h_io (write, f32 exact).
__global__ __launch_bounds__(1024) void k_scan(const ushort* __restrict__ xg,
                                               const void* __restrict__ donep,
                                               const int* __restrict__ flagp,
                                               const float* __restrict__ h_in,
                                               const ushort* __restrict__ WhT,
                                               const float* __restrict__ bhn,
                                               ushort* __restrict__ ys,
                                               float* __restrict__ h_io,
                                               float* __restrict__ h_last,
                                               int t0, int steps){
  __shared__ __align__(16) float  h_f[16][DD];
  __shared__ __align__(16) ushort h_b[16][DD];
  const int tid = threadIdx.x;
  const int w = tid >> 6, l = tid & 63, l16 = l & 15, l4 = l >> 4;
  const int b0 = blockIdx.x * 16;
  const int use8 = *flagp;
  const unsigned char* d8 = (const unsigned char*)donep;
  const int* d32 = (const int*)donep;

  for(int e = tid; e < 16*DD; e += 1024){
    int b = e >> 9, d = e & (DD-1);
    float v = h_in[(size_t)(b0 + b)*DD + d];
    h_f[b][d] = v; h_b[b][d] = f2b(v);
  }
  __syncthreads();

  const int dbase = w * 32;
  const ushort* bp[6];
  #pragma unroll
  for(int g=0; g<3; g++)
    #pragma unroll
    for(int nt=0; nt<2; nt++)
      bp[g*2+nt] = WhT + (size_t)(g*DD + dbase + nt*16 + l16) * DD;

  for(int tl = 0; tl < steps; tl++){
    const int drow = (t0 + tl)*BB + b0;
    const bool dnA = use8 ? (d8[drow + l16] != 0) : (d32[drow + l16] != 0);

    f32x4 acc[3][2] = {};
    const short8 zf = {0,0,0,0,0,0,0,0};
    for(int k0 = 0; k0 < DD; k0 += 32){
      const int kb = k0 + l4*8;
      short8 a = *(const short8*)&h_b[l16][kb];
      if(dnA) a = zf;   // reset-carry folded into A operand
      #pragma unroll
      for(int g=0; g<3; g++)
        #pragma unroll
        for(int nt=0; nt<2; nt++){
          const short8 b = *(const short8*)(bp[g*2+nt] + kb);
          acc[g][nt] = __builtin_amdgcn_mfma_f32_16x16x32_bf16(a, b, acc[g][nt], 0, 0, 0);
        }
    }

    // phase A epilogue: compute h_new into registers (reads h_f / xg / done)
    float hnew[2][4];
    #pragma unroll
    for(int nt=0; nt<2; nt++){
      const int d = dbase + nt*16 + l16;
      const float bh = bhn[d];
      #pragma unroll
      for(int r=0; r<4; r++){
        const int brow = l4*4 + r;
        const bool dn = use8 ? (d8[drow + brow] != 0) : (d32[drow + brow] != 0);
        const size_t rowl = (size_t)(tl*BB + b0 + brow);
        const float xr = b2f(xg[rowl*(3*DD) + d]);
        const float xz = b2f(xg[rowl*(3*DD) + DD + d]);
        const float xn = b2f(xg[rowl*(3*DD) + 2*DD + d]);
        const float hold = dn ? 0.f : h_f[brow][d];
        const float rg = sigm(xr + acc[0][nt][r]);
        const float zg = sigm(xz + acc[1][nt][r]);
        const float ng = tanh_f(xn + rg*(acc[2][nt][r] + bh));
        hnew[nt][r] = (1.f - zg)*ng + zg*hold;
      }
    }
    __syncthreads();   // all reads of h_f/h_b done
    // phase B: write state
    #pragma unroll
    for(int nt=0; nt<2; nt++){
      const int d = dbase + nt*16 + l16;
      #pragma unroll
      for(int r=0; r<4; r++){
        const int brow = l4*4 + r;
        const size_t rowl = (size_t)(tl*BB + b0 + brow);
        const float hv = hnew[nt][r];
        h_f[brow][d] = hv;
        h_b[brow][d] = f2b(hv);
        ys[rowl*DD + d] = f2b(hv);
      }
    }
    __syncthreads();   // writes visible before next step's reads
  }

  for(int e = tid; e < 16*DD; e += 1024){
    int b = e >> 9, d = e & (DD-1);
    float v = h_f[b][d];
    h_io[(size_t)(b0 + b)*DD + d] = v;
    h_last[(size_t)(b0 + b)*DD + d] = v;
  }
}

// ---------------- value GEMV: value[row] = critic[row,:] . W2 + b2 ----------------
__global__ __launch_bounds__(256) void k_value(const ushort* __restrict__ critic,
                                               const float* __restrict__ W2,
                                               const float* __restrict__ b2,
                                               float* __restrict__ val){
  const int w = threadIdx.x >> 6, l = threadIdx.x & 63;
  const size_t row = (size_t)blockIdx.x*4 + w;
  const ushort* cp = critic + row*HH + l*8;
  const float* wp = W2 + l*8;
  float s = 0.f;
  #pragma unroll
  for(int j=0;j<8;j++) s += b2f(cp[j]) * wp[j];
  for(int off=32; off; off>>=1) s += __shfl_down(s, off, 64);
  if(l == 0) val[row] = s + b2[0];
}

extern "C" void kernel_launch(void* const* d_in, const int* in_sizes, int n_in,
                              void* d_out, int out_size, void* d_ws, size_t ws_size,
                              hipStream_t stream){
  const float* obs    = (const float*)d_in[0];
  const void*  done   = d_in[1];
  const float* hstate = (const float*)d_in[2];
  const float* W_emb  = (const float*)d_in[3];
  const float* b_emb  = (const float*)d_in[4];
  const float* Wi     = (const float*)d_in[5];
  const float* bi     = (const float*)d_in[6];
  const float* Wh     = (const float*)d_in[7];
  const float* bhn    = (const float*)d_in[8];
  const float* W1     = (const float*)d_in[9];
  const float* b1     = (const float*)d_in[10];
  const float* W2     = (const float*)d_in[11];
  const float* b2     = (const float*)d_in[12];
  float* out = (float*)d_out;
  char*  ws  = (char*)d_ws;

  // ---- fixed ws region ----
  ushort* WembT = (ushort*)(ws + 0);           // 512*256*2   = 262144
  ushort* WiT   = (ushort*)(ws + 262144);      // 1536*512*2  = 1572864 -> 1835008
  ushort* WhT   = (ushort*)(ws + 1835008);     // 1536*512*2  = 1572864 -> 3407872
  ushort* W1T   = (ushort*)(ws + 3407872);     // 512*512*2   = 524288  -> 3932160
  int*    flag  = (int*)   (ws + 3932160);     // 4
  float*  hio   = (float*) (ws + 3936256);     // 256*512*4   = 524288  -> 4460544
  const size_t FIX = 4718592;                  // 4.5 MiB, aligned start of chunk region

  // ---- pick chunk length TC (timesteps) to fit ws_size ----
  // per-chunk bytes: emb TC*262144 + xg TC*786432 + ys TC*262144 (critic reuses emb)
  int TC = 0;
  {
    const int cands[6] = {512, 256, 128, 64, 32, 16};
    for(int i = 0; i < 6; i++){
      size_t need = FIX + (size_t)cands[i] * 1310720u;
      if(need <= ws_size){ TC = cands[i]; break; }
    }
  }
  if(TC == 0) return;  // ws too small even for TC=16 (~25.5MB) -> clean failure, not a fault

  ushort* emb_c  = (ushort*)(ws + FIX);
  ushort* xg_c   = (ushort*)(ws + FIX + (size_t)TC*262144u);
  ushort* ys_c   = (ushort*)(ws + FIX + (size_t)TC*1048576u);
  ushort* crit_c = emb_c;   // reuse: emb dead after xg GEMM of the chunk

  // ---- weight prep (once) ----
  k_transpose_bf16<<<(OBSD*DD+255)/256, 256, 0, stream>>>(W_emb, WembT, OBSD, DD);
  k_transpose_bf16<<<(DD*3*DD+255)/256, 256, 0, stream>>>(Wi, WiT, DD, 3*DD);
  k_transpose_bf16<<<(DD*3*DD+255)/256, 256, 0, stream>>>(Wh, WhT, DD, 3*DD);
  k_transpose_bf16<<<(DD*HH+255)/256, 256, 0, stream>>>(W1, W1T, DD, HH);
  k_detect<<<1, 256, 0, stream>>>((const int*)done, flag);

  const int nchunks = TT / TC;
  for(int c = 0; c < nchunks; c++){
    const int Mc = TC * BB;
    const size_t row0 = (size_t)c * Mc;
    // emb = relu(obs @ W_emb + b_emb)
    k_gemm<<<dim3(Mc/64, DD/64), 256, 0, stream>>>(obs + row0*OBSD, 1, WembT, b_emb,
                                                   emb_c, Mc, DD, OBSD, 1);
    // xg = emb @ Wi + bi
    k_gemm<<<dim3(Mc/64, (3*DD)/64), 256, 0, stream>>>(emb_c, 0, WiT, bi,
                                                       xg_c, Mc, 3*DD, DD, 0);
    // GRU scan chunk -> ys_c, h carried via hio (chunk 0 reads hstate)
    k_scan<<<16, 1024, 0, stream>>>(xg_c, done, flag,
                                    (c == 0) ? hstate : hio,
                                    WhT, bhn, ys_c, hio, out, c*TC, TC);
    // critic = relu(ys @ W1 + b1)
    k_gemm<<<dim3(Mc/64, HH/64), 256, 0, stream>>>(ys_c, 0, W1T, b1,
                                                   crit_c, Mc, HH, DD, 1);
    // value = critic @ W2 + b2
    k_value<<<Mc/4, 256, 0, stream>>>(crit_c, W2, b2, out + (size_t)BB*DD + row0);
  }
}

// Round 3
// 18966.858 us; speedup vs baseline: 1.3382x; 1.3382x over previous
//
#include <hip/hip_runtime.h>

// Problem dims
#define TT   512
#define BB   256
#define OBSD 256
#define DD   512
#define HH   512
#define MROWS (TT*BB)   // 131072

typedef __attribute__((ext_vector_type(8))) short short8;
typedef __attribute__((ext_vector_type(4))) float f32x4;

__device__ __forceinline__ ushort f2b(float f){
  unsigned int x = __float_as_uint(f);
  x = (x + 0x7fffu + ((x >> 16) & 1u)) >> 16;   // RNE
  return (ushort)x;
}
__device__ __forceinline__ float b2f(ushort u){
  return __uint_as_float(((unsigned int)u) << 16);
}
__device__ __forceinline__ float sigm(float x){ return 1.f/(1.f + __expf(-x)); }
__device__ __forceinline__ float tanh_f(float x){ return 1.f - 2.f/(__expf(2.f*x) + 1.f); }

// ---------------- transpose f32 [K,N] -> bf16 [N,K] ----------------
__global__ void k_transpose_bf16(const float* __restrict__ W, ushort* __restrict__ Wt,
                                 int K, int N){
  int i = blockIdx.x*256 + threadIdx.x;
  if(i >= K*N) return;
  int k = i / N, n = i % N;
  Wt[(size_t)n*K + k] = f2b(W[i]);
}

// ---------------- detect done dtype (byte-packed vs 4-byte) ----------------
__global__ void k_detect(const int* __restrict__ done, int* __restrict__ flag){
  __shared__ int cnt;
  if(threadIdx.x == 0) cnt = 0;
  __syncthreads();
  int c = 0;
  for(int i = threadIdx.x; i < 32768; i += 256) c += (done[i] != 0);
  for(int off = 32; off; off >>= 1) c += __shfl_down(c, off, 64);
  if((threadIdx.x & 63) == 0) atomicAdd(&cnt, c);
  __syncthreads();
  if(threadIdx.x == 0) *flag = (cnt > 700) ? 1 : 0;  // 1 => byte-packed bools
}

// ---------------- generic MFMA GEMM (unchanged from r2) ----------------
__global__ __launch_bounds__(256) void k_gemm(const void* __restrict__ Av, int a_f32,
                                              const ushort* __restrict__ Bt,
                                              const float* __restrict__ bias,
                                              ushort* __restrict__ C,
                                              int M, int N, int K, int relu){
  const int w = threadIdx.x >> 6, l = threadIdx.x & 63;
  const int l16 = l & 15, l4 = l >> 4;
  const size_t m0 = (size_t)blockIdx.x*64 + w*16;
  const size_t n0 = (size_t)blockIdx.y*64;
  const size_t arow = m0 + l16;
  f32x4 acc[4] = {};
  const ushort* bp[4];
  #pragma unroll
  for(int nt=0; nt<4; nt++) bp[nt] = Bt + (n0 + nt*16 + l16)*(size_t)K;

  for(int k0 = 0; k0 < K; k0 += 32){
    const int kb = k0 + l4*8;
    short8 a;
    if(a_f32){
      const float* A = (const float*)Av + arow*(size_t)K + kb;
      union{ short8 v; ushort u[8]; } t;
      #pragma unroll
      for(int j=0;j<8;j++) t.u[j] = f2b(A[j]);
      a = t.v;
    } else {
      a = *(const short8*)((const ushort*)Av + arow*(size_t)K + kb);
    }
    #pragma unroll
    for(int nt=0; nt<4; nt++){
      const short8 b = *(const short8*)(bp[nt] + kb);
      acc[nt] = __builtin_amdgcn_mfma_f32_16x16x32_bf16(a, b, acc[nt], 0, 0, 0);
    }
  }
  #pragma unroll
  for(int nt=0; nt<4; nt++){
    const int col = (int)n0 + nt*16 + l16;
    const float bv = bias[col];
    #pragma unroll
    for(int r=0; r<4; r++){
      const size_t row = m0 + l4*4 + r;
      float v = acc[nt][r] + bv;
      if(relu) v = fmaxf(v, 0.f);
      C[row*(size_t)N + col] = f2b(v);
    }
  }
}

// ======================= cooperative GRU scan =======================
// 256 blocks x 128 thr. block = (g = bid>>5: batch group of 32 rows,
// ds = bid&31: d-slice of 16 cols). WhT slice [48 rows x 512] persists in LDS
// (XOR-swizzled). h ping-pongs in global bf16 (double buffer); per-group
// 32-block barrier each step via device-scope atomics.
__device__ __forceinline__ void group_barrier(int* cnt, int target, int tid){
  __threadfence();
  __syncthreads();
  if(tid == 0){
    __hip_atomic_fetch_add(cnt, 1, __ATOMIC_RELEASE, __HIP_MEMORY_SCOPE_AGENT);
    while(__hip_atomic_load(cnt, __ATOMIC_ACQUIRE, __HIP_MEMORY_SCOPE_AGENT) < target){
      __builtin_amdgcn_s_sleep(8);
    }
  }
  __syncthreads();
}

__global__ __launch_bounds__(128) void k_scan_coop(
    const ushort* __restrict__ xg, const void* __restrict__ donep,
    const int* __restrict__ flagp, const float* __restrict__ h_in,
    const ushort* __restrict__ WhT, const float* __restrict__ bhn,
    ushort* __restrict__ ys, float* __restrict__ h_io,
    float* __restrict__ h_last, ushort* __restrict__ hbf,   // [2][256][512] bf16
    int t0, int steps, int* __restrict__ cntbase){
  __shared__ __align__(16) ushort whs[48*512];   // 48KB
  const int tid = threadIdx.x;
  const int m = tid >> 6, l = tid & 63, l16 = l & 15, l4 = l >> 4;
  const int bid = blockIdx.x;
  const int g = bid >> 5, ds = bid & 31;
  const int use8 = *flagp;
  const unsigned char* d8 = (const unsigned char*)donep;
  const int* d32 = (const int*)donep;
  int* cnt = cntbase + g*64;   // 256B apart

  // ---- stage WhT slice into LDS, swizzled ----
  for(int e = tid; e < 3072; e += 128){
    const int lr = e >> 6;              // local row 0..47
    const int kc = (e & 63) << 3;       // k 0..504 step 8
    const int grow_w = (lr >> 4)*DD + ds*16 + (lr & 15);
    short8 v = *(const short8*)(WhT + (size_t)grow_w*DD + kc);
    int boff = ((lr << 10) + (kc << 1)) ^ ((lr & 7) << 4);
    *(short8*)((char*)whs + boff) = v;
  }

  // ---- prologue: load h f32 for own slice, publish bf16 into hbf[0] ----
  const int d = ds*16 + l16;
  const int row_e = g*32 + m*16 + l4*4;          // first of 4 epilogue rows
  const float bh = bhn[d];
  float hf[4];
  #pragma unroll
  for(int i=0;i<4;i++){
    float v = h_in[(size_t)(row_e + i)*DD + d];
    hf[i] = v;
    hbf[(size_t)(row_e + i)*DD + d] = f2b(v);
  }
  int bar = 32;
  group_barrier(cnt, bar, tid);   // whs staged (block) + hbf[0] published (group)

  // b-frag swizzle bases (gate gi -> local row gi*16 + l16)
  int rb[3], sw[3];
  #pragma unroll
  for(int gi=0; gi<3; gi++){
    const int lr = gi*16 + l16;
    rb[gi] = lr << 10;
    sw[gi] = (lr & 7) << 4;
  }
  const int row_a = g*32 + m*16 + l16;   // A-frag row for this lane

  for(int tl = 0; tl < steps; tl++){
    const int t = t0 + tl;
    const ushort* hcur = hbf + (size_t)(tl & 1)*MROWS;     // [256][512] (uses BB*DD)
    ushort* hnxt = (ushort*)hbf + (size_t)((tl & 1)^1)*BB*DD;
    const bool dnA = use8 ? (d8[t*BB + row_a] != 0) : (d32[t*BB + row_a] != 0);

    f32x4 acc[3] = {};
    const short8 zf = {0,0,0,0,0,0,0,0};
    #pragma unroll 4
    for(int k0 = 0; k0 < DD; k0 += 32){
      const int kb = k0 + l4*8;
      short8 a = *(const short8*)(hcur + (size_t)row_a*DD + kb);
      if(dnA) a = zf;
      #pragma unroll
      for(int gi=0; gi<3; gi++){
        const int boff = (rb[gi] + (kb << 1)) ^ sw[gi];
        const short8 b = *(const short8*)((const char*)whs + boff);
        acc[gi] = __builtin_amdgcn_mfma_f32_16x16x32_bf16(a, b, acc[gi], 0, 0, 0);
      }
    }

    #pragma unroll
    for(int i=0;i<4;i++){
      const int row = row_e + i;
      const bool dn = use8 ? (d8[t*BB + row] != 0) : (d32[t*BB + row] != 0);
      const size_t xbase = ((size_t)tl*BB + row)*(3*DD) + d;
      const float xr = b2f(xg[xbase]);
      const float xz = b2f(xg[xbase + DD]);
      const float xn = b2f(xg[xbase + 2*DD]);
      const float hold = dn ? 0.f : hf[i];
      const float rg = sigm(xr + acc[0][i]);
      const float zg = sigm(xz + acc[1][i]);
      const float ng = tanh_f(xn + rg*(acc[2][i] + bh));
      const float hv = (1.f - zg)*ng + zg*hold;
      hf[i] = hv;
      const ushort hb = f2b(hv);
      hnxt[(size_t)row*DD + d] = hb;
      ys[((size_t)tl*BB + row)*DD + d] = hb;
    }
    bar += 32;
    group_barrier(cnt, bar, tid);
  }

  #pragma unroll
  for(int i=0;i<4;i++){
    h_io[(size_t)(row_e + i)*DD + d] = hf[i];
    h_last[(size_t)(row_e + i)*DD + d] = hf[i];
  }
}

// ---------------- fallback GRU scan (round-2 version, 16 blocks) ----------------
__global__ __launch_bounds__(1024) void k_scan(const ushort* __restrict__ xg,
                                               const void* __restrict__ donep,
                                               const int* __restrict__ flagp,
                                               const float* __restrict__ h_in,
                                               const ushort* __restrict__ WhT,
                                               const float* __restrict__ bhn,
                                               ushort* __restrict__ ys,
                                               float* __restrict__ h_io,
                                               float* __restrict__ h_last,
                                               int t0, int steps){
  __shared__ __align__(16) float  h_f[16][DD];
  __shared__ __align__(16) ushort h_b[16][DD];
  const int tid = threadIdx.x;
  const int w = tid >> 6, l = tid & 63, l16 = l & 15, l4 = l >> 4;
  const int b0 = blockIdx.x * 16;
  const int use8 = *flagp;
  const unsigned char* d8 = (const unsigned char*)donep;
  const int* d32 = (const int*)donep;

  for(int e = tid; e < 16*DD; e += 1024){
    int b = e >> 9, dd = e & (DD-1);
    float v = h_in[(size_t)(b0 + b)*DD + dd];
    h_f[b][dd] = v; h_b[b][dd] = f2b(v);
  }
  __syncthreads();

  const int dbase = w * 32;
  const ushort* bp[6];
  #pragma unroll
  for(int g=0; g<3; g++)
    #pragma unroll
    for(int nt=0; nt<2; nt++)
      bp[g*2+nt] = WhT + (size_t)(g*DD + dbase + nt*16 + l16) * DD;

  for(int tl = 0; tl < steps; tl++){
    const int drow = (t0 + tl)*BB + b0;
    const bool dnA = use8 ? (d8[drow + l16] != 0) : (d32[drow + l16] != 0);
    f32x4 acc[3][2] = {};
    const short8 zf = {0,0,0,0,0,0,0,0};
    for(int k0 = 0; k0 < DD; k0 += 32){
      const int kb = k0 + l4*8;
      short8 a = *(const short8*)&h_b[l16][kb];
      if(dnA) a = zf;
      #pragma unroll
      for(int g=0; g<3; g++)
        #pragma unroll
        for(int nt=0; nt<2; nt++){
          const short8 b = *(const short8*)(bp[g*2+nt] + kb);
          acc[g][nt] = __builtin_amdgcn_mfma_f32_16x16x32_bf16(a, b, acc[g][nt], 0, 0, 0);
        }
    }
    float hnew[2][4];
    #pragma unroll
    for(int nt=0; nt<2; nt++){
      const int dd = dbase + nt*16 + l16;
      const float bh = bhn[dd];
      #pragma unroll
      for(int r=0; r<4; r++){
        const int brow = l4*4 + r;
        const bool dn = use8 ? (d8[drow + brow] != 0) : (d32[drow + brow] != 0);
        const size_t rowl = (size_t)(tl*BB + b0 + brow);
        const float xr = b2f(xg[rowl*(3*DD) + dd]);
        const float xz = b2f(xg[rowl*(3*DD) + DD + dd]);
        const float xn = b2f(xg[rowl*(3*DD) + 2*DD + dd]);
        const float hold = dn ? 0.f : h_f[brow][dd];
        const float rg = sigm(xr + acc[0][nt][r]);
        const float zg = sigm(xz + acc[1][nt][r]);
        const float ng = tanh_f(xn + rg*(acc[2][nt][r] + bh));
        hnew[nt][r] = (1.f - zg)*ng + zg*hold;
      }
    }
    __syncthreads();
    #pragma unroll
    for(int nt=0; nt<2; nt++){
      const int dd = dbase + nt*16 + l16;
      #pragma unroll
      for(int r=0; r<4; r++){
        const int brow = l4*4 + r;
        const size_t rowl = (size_t)(tl*BB + b0 + brow);
        const float hv = hnew[nt][r];
        h_f[brow][dd] = hv;
        h_b[brow][dd] = f2b(hv);
        ys[rowl*DD + dd] = f2b(hv);
      }
    }
    __syncthreads();
  }

  for(int e = tid; e < 16*DD; e += 1024){
    int b = e >> 9, dd = e & (DD-1);
    float v = h_f[b][dd];
    h_io[(size_t)(b0 + b)*DD + dd] = v;
    h_last[(size_t)(b0 + b)*DD + dd] = v;
  }
}

// ---------------- value GEMV ----------------
__global__ __launch_bounds__(256) void k_value(const ushort* __restrict__ critic,
                                               const float* __restrict__ W2,
                                               const float* __restrict__ b2,
                                               float* __restrict__ val){
  const int w = threadIdx.x >> 6, l = threadIdx.x & 63;
  const size_t row = (size_t)blockIdx.x*4 + w;
  const ushort* cp = critic + row*HH + l*8;
  const float* wp = W2 + l*8;
  float s = 0.f;
  #pragma unroll
  for(int j=0;j<8;j++) s += b2f(cp[j]) * wp[j];
  for(int off=32; off; off>>=1) s += __shfl_down(s, off, 64);
  if(l == 0) val[row] = s + b2[0];
}

extern "C" void kernel_launch(void* const* d_in, const int* in_sizes, int n_in,
                              void* d_out, int out_size, void* d_ws, size_t ws_size,
                              hipStream_t stream){
  const float* obs    = (const float*)d_in[0];
  const void*  done   = d_in[1];
  const float* hstate = (const float*)d_in[2];
  const float* W_emb  = (const float*)d_in[3];
  const float* b_emb  = (const float*)d_in[4];
  const float* Wi     = (const float*)d_in[5];
  const float* bi     = (const float*)d_in[6];
  const float* Wh     = (const float*)d_in[7];
  const float* bhn    = (const float*)d_in[8];
  const float* W1     = (const float*)d_in[9];
  const float* b1     = (const float*)d_in[10];
  const float* W2     = (const float*)d_in[11];
  const float* b2     = (const float*)d_in[12];
  float* out = (float*)d_out;
  char*  ws  = (char*)d_ws;

  // ---- fixed ws region ----
  ushort* WembT = (ushort*)(ws + 0);           // 262144
  ushort* WiT   = (ushort*)(ws + 262144);      // -> 1835008
  ushort* WhT   = (ushort*)(ws + 1835008);     // -> 3407872
  ushort* W1T   = (ushort*)(ws + 3407872);     // -> 3932160
  int*    flag  = (int*)   (ws + 3932160);     // 4
  float*  hio   = (float*) (ws + 3936256);     // -> 4460544
  ushort* hbf   = (ushort*)(ws + 4460544);     // 2*256*512*2 = 524288 -> 4984832
  int*    cnt   = (int*)   (ws + 4984832);     // 8 groups * 256B = 2048 -> 4986880
  const size_t FIX = 5242880;                  // 5 MiB

  int TC = 0;
  {
    const int cands[6] = {512, 256, 128, 64, 32, 16};
    for(int i = 0; i < 6; i++){
      size_t need = FIX + (size_t)cands[i] * 1310720u;
      if(need <= ws_size){ TC = cands[i]; break; }
    }
  }
  if(TC == 0) return;

  ushort* emb_c  = (ushort*)(ws + FIX);
  ushort* xg_c   = (ushort*)(ws + FIX + (size_t)TC*262144u);
  ushort* ys_c   = (ushort*)(ws + FIX + (size_t)TC*1048576u);
  ushort* crit_c = emb_c;

  k_transpose_bf16<<<(OBSD*DD+255)/256, 256, 0, stream>>>(W_emb, WembT, OBSD, DD);
  k_transpose_bf16<<<(DD*3*DD+255)/256, 256, 0, stream>>>(Wi, WiT, DD, 3*DD);
  k_transpose_bf16<<<(DD*3*DD+255)/256, 256, 0, stream>>>(Wh, WhT, DD, 3*DD);
  k_transpose_bf16<<<(DD*HH+255)/256, 256, 0, stream>>>(W1, W1T, DD, HH);
  k_detect<<<1, 256, 0, stream>>>((const int*)done, flag);

  const int nchunks = TT / TC;
  for(int c = 0; c < nchunks; c++){
    const int Mc = TC * BB;
    const size_t row0 = (size_t)c * Mc;
    k_gemm<<<dim3(Mc/64, DD/64), 256, 0, stream>>>(obs + row0*OBSD, 1, WembT, b_emb,
                                                   emb_c, Mc, DD, OBSD, 1);
    k_gemm<<<dim3(Mc/64, (3*DD)/64), 256, 0, stream>>>(emb_c, 0, WiT, bi,
                                                       xg_c, Mc, 3*DD, DD, 0);
    // ---- cooperative scan (fallback to 16-block scan on launch error) ----
    {
      const ushort* xg_a = xg_c;  const void* done_a = done;
      const int* flag_a = flag;   const float* hin_a = (c == 0) ? hstate : hio;
      const ushort* wht_a = WhT;  const float* bhn_a = bhn;
      ushort* ys_a = ys_c;        float* hio_a = hio;
      float* hl_a = out;          ushort* hbf_a = hbf;
      int t0_a = c*TC;            int steps_a = TC;
      int* cnt_a = cnt;
      void* args[13] = { (void*)&xg_a, (void*)&done_a, (void*)&flag_a, (void*)&hin_a,
                         (void*)&wht_a, (void*)&bhn_a, (void*)&ys_a, (void*)&hio_a,
                         (void*)&hl_a, (void*)&hbf_a, (void*)&t0_a, (void*)&steps_a,
                         (void*)&cnt_a };
      hipMemsetAsync(cnt, 0, 2048, stream);
      hipError_t err = hipLaunchCooperativeKernel((const void*)k_scan_coop,
                                                  dim3(256), dim3(128), args, 0, stream);
      if(err != hipSuccess){
        k_scan<<<16, 1024, 0, stream>>>(xg_c, done, flag, hin_a, WhT, bhn,
                                        ys_c, hio, out, c*TC, TC);
      }
    }
    k_gemm<<<dim3(Mc/64, HH/64), 256, 0, stream>>>(ys_c, 0, W1T, b1,
                                                   crit_c, Mc, HH, DD, 1);
    k_value<<<Mc/4, 256, 0, stream>>>(crit_c, W2, b2, out + (size_t)BB*DD + row0);
  }
}

// Round 4
// 4974.747 us; speedup vs baseline: 5.1021x; 3.8126x over previous
//
#include <hip/hip_runtime.h>

// Problem dims
#define TT   512
#define BB   256
#define OBSD 256
#define DD   512
#define HH   512
#define MROWS (TT*BB)   // 131072

typedef __attribute__((ext_vector_type(8))) short short8;
typedef __attribute__((ext_vector_type(4))) float f32x4;

__device__ __forceinline__ ushort f2b(float f){
  unsigned int x = __float_as_uint(f);
  x = (x + 0x7fffu + ((x >> 16) & 1u)) >> 16;   // RNE
  return (ushort)x;
}
__device__ __forceinline__ float b2f(ushort u){
  return __uint_as_float(((unsigned int)u) << 16);
}
__device__ __forceinline__ float sigm(float x){ return 1.f/(1.f + __expf(-x)); }
__device__ __forceinline__ float tanh_f(float x){ return 1.f - 2.f/(__expf(2.f*x) + 1.f); }

// ---------------- transpose f32 [K,N] -> bf16 [N,K] ----------------
__global__ void k_transpose_bf16(const float* __restrict__ W, ushort* __restrict__ Wt,
                                 int K, int N){
  int i = blockIdx.x*256 + threadIdx.x;
  if(i >= K*N) return;
  int k = i / N, n = i % N;
  Wt[(size_t)n*K + k] = f2b(W[i]);
}

// ---------------- detect done dtype (byte-packed vs 4-byte) ----------------
__global__ void k_detect(const int* __restrict__ done, int* __restrict__ flag){
  __shared__ int cnt;
  if(threadIdx.x == 0) cnt = 0;
  __syncthreads();
  int c = 0;
  for(int i = threadIdx.x; i < 32768; i += 256) c += (done[i] != 0);
  for(int off = 32; off; off >>= 1) c += __shfl_down(c, off, 64);
  if((threadIdx.x & 63) == 0) atomicAdd(&cnt, c);
  __syncthreads();
  if(threadIdx.x == 0) *flag = (cnt > 700) ? 1 : 0;  // 1 => byte-packed bools
}

// ---------------- generic MFMA GEMM ----------------
// xg_layout=1: write C in scan-native layout [t][ds][g][gate][r32][c16]
__global__ __launch_bounds__(256) void k_gemm(const void* __restrict__ Av, int a_f32,
                                              const ushort* __restrict__ Bt,
                                              const float* __restrict__ bias,
                                              ushort* __restrict__ C,
                                              int M, int N, int K, int relu,
                                              int xg_layout){
  const int w = threadIdx.x >> 6, l = threadIdx.x & 63;
  const int l16 = l & 15, l4 = l >> 4;
  const size_t m0 = (size_t)blockIdx.x*64 + w*16;
  const size_t n0 = (size_t)blockIdx.y*64;
  const size_t arow = m0 + l16;
  f32x4 acc[4] = {};
  const ushort* bp[4];
  #pragma unroll
  for(int nt=0; nt<4; nt++) bp[nt] = Bt + (n0 + nt*16 + l16)*(size_t)K;

  for(int k0 = 0; k0 < K; k0 += 32){
    const int kb = k0 + l4*8;
    short8 a;
    if(a_f32){
      const float* A = (const float*)Av + arow*(size_t)K + kb;
      union{ short8 v; ushort u[8]; } t;
      #pragma unroll
      for(int j=0;j<8;j++) t.u[j] = f2b(A[j]);
      a = t.v;
    } else {
      a = *(const short8*)((const ushort*)Av + arow*(size_t)K + kb);
    }
    #pragma unroll
    for(int nt=0; nt<4; nt++){
      const short8 b = *(const short8*)(bp[nt] + kb);
      acc[nt] = __builtin_amdgcn_mfma_f32_16x16x32_bf16(a, b, acc[nt], 0, 0, 0);
    }
  }
  #pragma unroll
  for(int nt=0; nt<4; nt++){
    const int col = (int)n0 + nt*16 + l16;
    const float bv = bias[col];
    #pragma unroll
    for(int r=0; r<4; r++){
      const size_t row = m0 + l4*4 + r;
      float v = acc[nt][r] + bv;
      if(relu) v = fmaxf(v, 0.f);
      size_t addr;
      if(xg_layout){
        const int rr = (int)row, tl = rr >> 8, brow = rr & 255;
        const int gg = brow >> 5, r32 = brow & 31;
        const int gate = col >> 9, cw = col & 511, ds2 = cw >> 4, c16 = cw & 15;
        addr = ((((size_t)tl*32 + ds2)*8 + gg)*3 + gate)*512 + r32*16 + c16;
      } else {
        addr = row*(size_t)N + col;
      }
      C[addr] = f2b(v);
    }
  }
}

// ======================= cooperative GRU scan =======================
// 256 blocks x 128 thr. block = (g = bid>>5: 32 batch rows, ds = bid&31: 16 d-cols).
// WhT slice [48x512] persistent in LDS (XOR-swizzled). h ping-pong in global bf16
// via sc0/sc1 (Infinity-Cache coherent) ops. xg staged per-step into LDS via
// global_load_lds from scan-native layout. done staged to LDS once per chunk.
__device__ __forceinline__ void group_barrier(int* cnt, int target, int tid){
  asm volatile("s_waitcnt vmcnt(0)" ::: "memory");
  __syncthreads();
  if(tid == 0){
    __hip_atomic_fetch_add(cnt, 1, __ATOMIC_RELAXED, __HIP_MEMORY_SCOPE_AGENT);
    while(__hip_atomic_load(cnt, __ATOMIC_RELAXED, __HIP_MEMORY_SCOPE_AGENT) < target)
      __builtin_amdgcn_s_sleep(2);
  }
  __syncthreads();
}

#define ALD(v, off) asm volatile("global_load_dwordx4 %0, %1, off offset:" off " sc0 sc1" \
                                 : "=&v"(v) : "v"(abase))

__global__ __launch_bounds__(128, 1) void k_scan_coop(
    const ushort* __restrict__ xg,        // scan-native layout, chunk-local
    const void* __restrict__ donep,
    const int* __restrict__ flagp, const float* __restrict__ h_in,
    const ushort* __restrict__ WhT, const float* __restrict__ bhn,
    ushort* __restrict__ ys, float* __restrict__ h_io,
    float* __restrict__ h_last, ushort* __restrict__ hbf,   // [2][256][512] bf16
    int t0, int steps, int* __restrict__ cntbase){
  __shared__ __align__(16) ushort whs[48*512];     // 48 KB
  __shared__ __align__(16) ushort xgs[2][1536];    // 6 KB double-buffered xg slice
  __shared__ unsigned char dns[512*32];            // 16 KB done bits for this group
  const int tid = threadIdx.x;
  const int m = tid >> 6, l = tid & 63, l16 = l & 15, l4 = l >> 4;
  const int bid = blockIdx.x;
  const int g = bid >> 5, ds = bid & 31;
  const int use8 = *flagp;
  const unsigned char* d8 = (const unsigned char*)donep;
  const int* d32 = (const int*)donep;
  int* cnt = cntbase + g*64;   // 256B apart

  // ---- stage WhT slice into LDS, swizzled ----
  for(int e = tid; e < 3072; e += 128){
    const int lr = e >> 6;              // local row 0..47
    const int kc = (e & 63) << 3;       // k 0..504 step 8
    const int grow_w = (lr >> 4)*DD + ds*16 + (lr & 15);
    short8 v = *(const short8*)(WhT + (size_t)grow_w*DD + kc);
    int boff = ((lr << 10) + (kc << 1)) ^ ((lr & 7) << 4);
    *(short8*)((char*)whs + boff) = v;
  }
  // ---- stage done bits for this group's 32 rows x steps ----
  for(int e = tid; e < steps*32; e += 128){
    const int tloc = e >> 5, r = e & 31;
    const int gi = (t0 + tloc)*BB + g*32 + r;
    dns[e] = use8 ? (d8[gi] != 0) : (d32[gi] != 0);
  }

  // ---- prologue: load h f32 for own slice, publish bf16 into hbf[0] (coherent) ----
  const int d = ds*16 + l16;
  const int r32e = m*16 + l4*4;                   // first of 4 epilogue rows (local)
  const int row_e = g*32 + r32e;
  const float bh = bhn[d];
  float hf[4];
  #pragma unroll
  for(int i=0;i<4;i++){
    float v = h_in[(size_t)(row_e + i)*DD + d];
    hf[i] = v;
    const ushort* p = hbf + (size_t)(row_e + i)*DD + d;
    unsigned hv32 = f2b(v);
    asm volatile("global_store_short %0, %1, off sc0 sc1" :: "v"(p), "v"(hv32) : "memory");
  }
  // ---- stage xg slice for step 0 into xgs[0] ----
  {
    const ushort* sl = xg + (((size_t)0*32 + ds)*8 + g)*1536;
    __builtin_amdgcn_global_load_lds(
      (const __attribute__((address_space(1))) void*)(sl + m*512 + l*8),
      (__attribute__((address_space(3))) void*)(&xgs[0][m*512]), 16, 0, 0);
    if(m == 0)
      __builtin_amdgcn_global_load_lds(
        (const __attribute__((address_space(1))) void*)(sl + 1024 + l*8),
        (__attribute__((address_space(3))) void*)(&xgs[0][1024]), 16, 0, 0);
  }
  int bar = 32;
  group_barrier(cnt, bar, tid);   // drains stores+loads (vmcnt0), group sync

  // b-frag swizzle bases (gate gi -> local row gi*16 + l16)
  int rb[3], sw[3];
  #pragma unroll
  for(int gi=0; gi<3; gi++){
    const int lr = gi*16 + l16;
    rb[gi] = lr << 10;
    sw[gi] = (lr & 7) << 4;
  }
  const int row_a = g*32 + m*16 + l16;   // A-frag row for this lane
  const ushort* hb0 = hbf;
  const ushort* hb1 = hbf + (size_t)BB*DD;
  int cur = 0;

  for(int tl = 0; tl < steps; tl++){
    const ushort* hcur = (tl & 1) ? hb1 : hb0;
    ushort* hnxt = (ushort*)((tl & 1) ? hb0 : hb1);
    const bool dnA = dns[tl*32 + (m*16 + l16)];

    // ---- A-fragments: 16x global_load_dwordx4 sc0 sc1 (Infinity-Cache coherent) ----
    const ushort* abase = hcur + (size_t)row_a*DD + l4*8;
    short8 a0,a1,a2,a3,a4,a5,a6,a7,a8,a9,a10,a11,a12,a13,a14,a15;
    ALD(a0,"0");    ALD(a1,"64");   ALD(a2,"128");  ALD(a3,"192");
    ALD(a4,"256");  ALD(a5,"320");  ALD(a6,"384");  ALD(a7,"448");
    ALD(a8,"512");  ALD(a9,"576");  ALD(a10,"640"); ALD(a11,"704");
    ALD(a12,"768"); ALD(a13,"832"); ALD(a14,"896"); ALD(a15,"960");
    asm volatile("s_waitcnt vmcnt(0)" ::: "memory");
    __builtin_amdgcn_sched_barrier(0);

    if(__builtin_expect(dnA, 0)){
      const short8 z = {0,0,0,0,0,0,0,0};
      a0=z;a1=z;a2=z;a3=z;a4=z;a5=z;a6=z;a7=z;
      a8=z;a9=z;a10=z;a11=z;a12=z;a13=z;a14=z;a15=z;
    }

    // ---- prefetch next step's xg slice into the other LDS buffer ----
    if(tl + 1 < steps){
      const int nb = cur ^ 1;
      const ushort* sl = xg + (((size_t)(tl+1)*32 + ds)*8 + g)*1536;
      __builtin_amdgcn_global_load_lds(
        (const __attribute__((address_space(1))) void*)(sl + m*512 + l*8),
        (__attribute__((address_space(3))) void*)(&xgs[nb][m*512]), 16, 0, 0);
      if(m == 0)
        __builtin_amdgcn_global_load_lds(
          (const __attribute__((address_space(1))) void*)(sl + 1024 + l*8),
          (__attribute__((address_space(3))) void*)(&xgs[nb][1024]), 16, 0, 0);
    }

    // ---- 48 MFMA: 16 k-steps x 3 gates ----
    f32x4 acc[3] = {};
    #define STEPK(ak, k0lit) { \
      const int kboff = ((k0lit + l4*8) << 1); \
      _Pragma("unroll") \
      for(int gi=0; gi<3; gi++){ \
        const short8 b = *(const short8*)((const char*)whs + ((rb[gi] + kboff) ^ sw[gi])); \
        acc[gi] = __builtin_amdgcn_mfma_f32_16x16x32_bf16(ak, b, acc[gi], 0, 0, 0); \
      } }
    STEPK(a0,0)    STEPK(a1,32)   STEPK(a2,64)   STEPK(a3,96)
    STEPK(a4,128)  STEPK(a5,160)  STEPK(a6,192)  STEPK(a7,224)
    STEPK(a8,256)  STEPK(a9,288)  STEPK(a10,320) STEPK(a11,352)
    STEPK(a12,384) STEPK(a13,416) STEPK(a14,448) STEPK(a15,480)
    #undef STEPK

    // ---- epilogue: gates from LDS xg, write h (coherent) + ys (plain) ----
    #pragma unroll
    for(int i=0;i<4;i++){
      const int r32 = r32e + i;
      const int row = g*32 + r32;
      const bool dn = dns[tl*32 + r32];
      const float xr = b2f(xgs[cur][       r32*16 + l16]);
      const float xz = b2f(xgs[cur][ 512 + r32*16 + l16]);
      const float xn = b2f(xgs[cur][1024 + r32*16 + l16]);
      const float hold = dn ? 0.f : hf[i];
      const float rg = sigm(xr + acc[0][i]);
      const float zg = sigm(xz + acc[1][i]);
      const float ng = tanh_f(xn + rg*(acc[2][i] + bh));
      const float hv = (1.f - zg)*ng + zg*hold;
      hf[i] = hv;
      const ushort hb = f2b(hv);
      const ushort* p = hnxt + (size_t)row*DD + d;
      unsigned hv32 = hb;
      asm volatile("global_store_short %0, %1, off sc0 sc1" :: "v"(p), "v"(hv32) : "memory");
      ys[((size_t)tl*BB + row)*DD + d] = hb;
    }
    bar += 32;
    group_barrier(cnt, bar, tid);
    cur ^= 1;
  }

  #pragma unroll
  for(int i=0;i<4;i++){
    h_io[(size_t)(row_e + i)*DD + d] = hf[i];
    h_last[(size_t)(row_e + i)*DD + d] = hf[i];
  }
}

// ---------------- fallback GRU scan (16 blocks; scan-native xg layout) ----------------
__global__ __launch_bounds__(1024) void k_scan(const ushort* __restrict__ xg,
                                               const void* __restrict__ donep,
                                               const int* __restrict__ flagp,
                                               const float* __restrict__ h_in,
                                               const ushort* __restrict__ WhT,
                                               const float* __restrict__ bhn,
                                               ushort* __restrict__ ys,
                                               float* __restrict__ h_io,
                                               float* __restrict__ h_last,
                                               int t0, int steps){
  __shared__ __align__(16) float  h_f[16][DD];
  __shared__ __align__(16) ushort h_b[16][DD];
  const int tid = threadIdx.x;
  const int w = tid >> 6, l = tid & 63, l16 = l & 15, l4 = l >> 4;
  const int b0 = blockIdx.x * 16;
  const int use8 = *flagp;
  const unsigned char* d8 = (const unsigned char*)donep;
  const int* d32 = (const int*)donep;

  for(int e = tid; e < 16*DD; e += 1024){
    int b = e >> 9, dd = e & (DD-1);
    float v = h_in[(size_t)(b0 + b)*DD + dd];
    h_f[b][dd] = v; h_b[b][dd] = f2b(v);
  }
  __syncthreads();

  const int dbase = w * 32;
  const ushort* bp[6];
  #pragma unroll
  for(int g=0; g<3; g++)
    #pragma unroll
    for(int nt=0; nt<2; nt++)
      bp[g*2+nt] = WhT + (size_t)(g*DD + dbase + nt*16 + l16) * DD;

  for(int tl = 0; tl < steps; tl++){
    const int drow = (t0 + tl)*BB + b0;
    const bool dnA = use8 ? (d8[drow + l16] != 0) : (d32[drow + l16] != 0);
    f32x4 acc[3][2] = {};
    const short8 zf = {0,0,0,0,0,0,0,0};
    for(int k0 = 0; k0 < DD; k0 += 32){
      const int kb = k0 + l4*8;
      short8 a = *(const short8*)&h_b[l16][kb];
      if(dnA) a = zf;
      #pragma unroll
      for(int g=0; g<3; g++)
        #pragma unroll
        for(int nt=0; nt<2; nt++){
          const short8 b = *(const short8*)(bp[g*2+nt] + kb);
          acc[g][nt] = __builtin_amdgcn_mfma_f32_16x16x32_bf16(a, b, acc[g][nt], 0, 0, 0);
        }
    }
    float hnew[2][4];
    #pragma unroll
    for(int nt=0; nt<2; nt++){
      const int dd = dbase + nt*16 + l16;
      const float bh = bhn[dd];
      const int ds2 = dd >> 4, c16 = dd & 15;
      #pragma unroll
      for(int r=0; r<4; r++){
        const int brow = l4*4 + r;
        const int grow = b0 + brow;
        const int gg = grow >> 5, r32 = grow & 31;
        const bool dn = use8 ? (d8[drow + brow] != 0) : (d32[drow + brow] != 0);
        const size_t sbase = (((size_t)tl*32 + ds2)*8 + gg)*1536 + r32*16 + c16;
        const float xr = b2f(xg[sbase]);
        const float xz = b2f(xg[sbase + 512]);
        const float xn = b2f(xg[sbase + 1024]);
        const float hold = dn ? 0.f : h_f[brow][dd];
        const float rg = sigm(xr + acc[0][nt][r]);
        const float zg = sigm(xz + acc[1][nt][r]);
        const float ng = tanh_f(xn + rg*(acc[2][nt][r] + bh));
        hnew[nt][r] = (1.f - zg)*ng + zg*hold;
      }
    }
    __syncthreads();
    #pragma unroll
    for(int nt=0; nt<2; nt++){
      const int dd = dbase + nt*16 + l16;
      #pragma unroll
      for(int r=0; r<4; r++){
        const int brow = l4*4 + r;
        const size_t rowl = (size_t)(tl*BB + b0 + brow);
        const float hv = hnew[nt][r];
        h_f[brow][dd] = hv;
        h_b[brow][dd] = f2b(hv);
        ys[rowl*DD + dd] = f2b(hv);
      }
    }
    __syncthreads();
  }

  for(int e = tid; e < 16*DD; e += 1024){
    int b = e >> 9, dd = e & (DD-1);
    float v = h_f[b][dd];
    h_io[(size_t)(b0 + b)*DD + dd] = v;
    h_last[(size_t)(b0 + b)*DD + dd] = v;
  }
}

// ---------------- value GEMV ----------------
__global__ __launch_bounds__(256) void k_value(const ushort* __restrict__ critic,
                                               const float* __restrict__ W2,
                                               const float* __restrict__ b2,
                                               float* __restrict__ val){
  const int w = threadIdx.x >> 6, l = threadIdx.x & 63;
  const size_t row = (size_t)blockIdx.x*4 + w;
  const ushort* cp = critic + row*HH + l*8;
  const float* wp = W2 + l*8;
  float s = 0.f;
  #pragma unroll
  for(int j=0;j<8;j++) s += b2f(cp[j]) * wp[j];
  for(int off=32; off; off>>=1) s += __shfl_down(s, off, 64);
  if(l == 0) val[row] = s + b2[0];
}

extern "C" void kernel_launch(void* const* d_in, const int* in_sizes, int n_in,
                              void* d_out, int out_size, void* d_ws, size_t ws_size,
                              hipStream_t stream){
  const float* obs    = (const float*)d_in[0];
  const void*  done   = d_in[1];
  const float* hstate = (const float*)d_in[2];
  const float* W_emb  = (const float*)d_in[3];
  const float* b_emb  = (const float*)d_in[4];
  const float* Wi     = (const float*)d_in[5];
  const float* bi     = (const float*)d_in[6];
  const float* Wh     = (const float*)d_in[7];
  const float* bhn    = (const float*)d_in[8];
  const float* W1     = (const float*)d_in[9];
  const float* b1     = (const float*)d_in[10];
  const float* W2     = (const float*)d_in[11];
  const float* b2     = (const float*)d_in[12];
  float* out = (float*)d_out;
  char*  ws  = (char*)d_ws;

  // ---- fixed ws region ----
  ushort* WembT = (ushort*)(ws + 0);           // 262144
  ushort* WiT   = (ushort*)(ws + 262144);      // -> 1835008
  ushort* WhT   = (ushort*)(ws + 1835008);     // -> 3407872
  ushort* W1T   = (ushort*)(ws + 3407872);     // -> 3932160
  int*    flag  = (int*)   (ws + 3932160);     // 4
  float*  hio   = (float*) (ws + 3936256);     // -> 4460544
  ushort* hbf   = (ushort*)(ws + 4460544);     // 2*256*512*2 = 524288 -> 4984832
  int*    cnt   = (int*)   (ws + 4984832);     // 8 groups * 256B -> 4986880
  const size_t FIX = 5242880;                  // 5 MiB

  int TC = 0;
  {
    const int cands[6] = {512, 256, 128, 64, 32, 16};
    for(int i = 0; i < 6; i++){
      size_t need = FIX + (size_t)cands[i] * 1310720u;
      if(need <= ws_size){ TC = cands[i]; break; }
    }
  }
  if(TC == 0) return;

  ushort* emb_c  = (ushort*)(ws + FIX);
  ushort* xg_c   = (ushort*)(ws + FIX + (size_t)TC*262144u);
  ushort* ys_c   = (ushort*)(ws + FIX + (size_t)TC*1048576u);
  ushort* crit_c = emb_c;

  k_transpose_bf16<<<(OBSD*DD+255)/256, 256, 0, stream>>>(W_emb, WembT, OBSD, DD);
  k_transpose_bf16<<<(DD*3*DD+255)/256, 256, 0, stream>>>(Wi, WiT, DD, 3*DD);
  k_transpose_bf16<<<(DD*3*DD+255)/256, 256, 0, stream>>>(Wh, WhT, DD, 3*DD);
  k_transpose_bf16<<<(DD*HH+255)/256, 256, 0, stream>>>(W1, W1T, DD, HH);
  k_detect<<<1, 256, 0, stream>>>((const int*)done, flag);

  const int nchunks = TT / TC;
  for(int c = 0; c < nchunks; c++){
    const int Mc = TC * BB;
    const size_t row0 = (size_t)c * Mc;
    k_gemm<<<dim3(Mc/64, DD/64), 256, 0, stream>>>(obs + row0*OBSD, 1, WembT, b_emb,
                                                   emb_c, Mc, DD, OBSD, 1, 0);
    // xg in scan-native layout
    k_gemm<<<dim3(Mc/64, (3*DD)/64), 256, 0, stream>>>(emb_c, 0, WiT, bi,
                                                       xg_c, Mc, 3*DD, DD, 0, 1);
    {
      const ushort* xg_a = xg_c;  const void* done_a = done;
      const int* flag_a = flag;   const float* hin_a = (c == 0) ? hstate : hio;
      const ushort* wht_a = WhT;  const float* bhn_a = bhn;
      ushort* ys_a = ys_c;        float* hio_a = hio;
      float* hl_a = out;          ushort* hbf_a = hbf;
      int t0_a = c*TC;            int steps_a = TC;
      int* cnt_a = cnt;
      void* args[13] = { (void*)&xg_a, (void*)&done_a, (void*)&flag_a, (void*)&hin_a,
                         (void*)&wht_a, (void*)&bhn_a, (void*)&ys_a, (void*)&hio_a,
                         (void*)&hl_a, (void*)&hbf_a, (void*)&t0_a, (void*)&steps_a,
                         (void*)&cnt_a };
      hipMemsetAsync(cnt, 0, 2048, stream);
      hipError_t err = hipLaunchCooperativeKernel((const void*)k_scan_coop,
                                                  dim3(256), dim3(128), args, 0, stream);
      if(err != hipSuccess){
        k_scan<<<16, 1024, 0, stream>>>(xg_c, done, flag, hin_a, WhT, bhn,
                                        ys_c, hio, out, c*TC, TC);
      }
    }
    k_gemm<<<dim3(Mc/64, HH/64), 256, 0, stream>>>(ys_c, 0, W1T, b1,
                                                   crit_c, Mc, HH, DD, 1, 0);
    k_value<<<Mc/4, 256, 0, stream>>>(crit_c, W2, b2, out + (size_t)BB*DD + row0);
  }
}

// Round 5
// 2903.731 us; speedup vs baseline: 8.7410x; 1.7132x over previous
//
#include <hip/hip_runtime.h>

// Problem dims
#define TT   512
#define BB   256
#define OBSD 256
#define DD   512
#define HH   512
#define MROWS (TT*BB)   // 131072

typedef __attribute__((ext_vector_type(8))) short short8;
typedef __attribute__((ext_vector_type(4))) float f32x4;

__device__ __forceinline__ ushort f2b(float f){
  unsigned int x = __float_as_uint(f);
  x = (x + 0x7fffu + ((x >> 16) & 1u)) >> 16;   // RNE
  return (ushort)x;
}
__device__ __forceinline__ float b2f(ushort u){
  return __uint_as_float(((unsigned int)u) << 16);
}
__device__ __forceinline__ float sigm(float x){ return 1.f/(1.f + __expf(-x)); }
__device__ __forceinline__ float tanh_f(float x){ return 1.f - 2.f/(__expf(2.f*x) + 1.f); }

// ---------------- transpose f32 [K,N] -> bf16 [N,K] ----------------
__global__ void k_transpose_bf16(const float* __restrict__ W, ushort* __restrict__ Wt,
                                 int K, int N){
  int i = blockIdx.x*256 + threadIdx.x;
  if(i >= K*N) return;
  int k = i / N, n = i % N;
  Wt[(size_t)n*K + k] = f2b(W[i]);
}

// ---------------- f32 -> bf16 elementwise (vectorized) ----------------
__global__ void k_f32_to_bf16(const float* __restrict__ in, ushort* __restrict__ out,
                              int n4){
  int i = blockIdx.x*256 + threadIdx.x;
  if(i >= n4) return;
  const float4 v = ((const float4*)in)[i];
  union{ ushort u[4]; uint2 d; } p;
  p.u[0] = f2b(v.x); p.u[1] = f2b(v.y); p.u[2] = f2b(v.z); p.u[3] = f2b(v.w);
  ((uint2*)out)[i] = p.d;
}

// ---------------- detect done dtype (byte-packed vs 4-byte) ----------------
__global__ void k_detect(const int* __restrict__ done, int* __restrict__ flag){
  __shared__ int cnt;
  if(threadIdx.x == 0) cnt = 0;
  __syncthreads();
  int c = 0;
  for(int i = threadIdx.x; i < 32768; i += 256) c += (done[i] != 0);
  for(int off = 32; off; off >>= 1) c += __shfl_down(c, off, 64);
  if((threadIdx.x & 63) == 0) atomicAdd(&cnt, c);
  __syncthreads();
  if(threadIdx.x == 0) *flag = (cnt > 700) ? 1 : 0;  // 1 => byte-packed bools
}

// ---------------- 128x128-tile LDS-staged MFMA GEMM (m97 structure) ----------------
// C[M,N] = op(A[M,K] @ Bt[N,K]^T + bias). A,Bt bf16 row-major K-contig. C bf16.
// 256 thr = 4 waves in 2x2; BK=32; global_load_lds width-16 staging; 2 barriers/K-step.
__global__ __launch_bounds__(256) void k_gemm128(const ushort* __restrict__ A,
                                                 const ushort* __restrict__ Bt,
                                                 const float* __restrict__ bias,
                                                 ushort* __restrict__ C,
                                                 int M, int N, int K, int relu,
                                                 int xg_layout){
  __shared__ __align__(16) ushort As[128*32];   // [row][k] 64B rows, 8KB
  __shared__ __align__(16) ushort Bs[128*32];
  const int tid = threadIdx.x;
  const int l = tid & 63, l16 = l & 15, l4 = l >> 4;
  const int w = tid >> 6, wr = w >> 1, wc = w & 1;
  const size_t m0 = (size_t)blockIdx.x*128, n0 = (size_t)blockIdx.y*128;
  f32x4 acc[4][4] = {};

  for(int k0 = 0; k0 < K; k0 += 32){
    #pragma unroll
    for(int j = 0; j < 2; j++){
      const int flat = tid*16 + j*4096;        // byte offset in 8KB tile
      const int row = flat >> 6;               // 64B per row
      const int ke  = (flat & 63) >> 1;        // k-elem within 32
      __builtin_amdgcn_global_load_lds(
        (const __attribute__((address_space(1))) void*)(A + (m0+row)*(size_t)K + k0 + ke),
        (__attribute__((address_space(3))) void*)((char*)As + flat), 16, 0, 0);
      __builtin_amdgcn_global_load_lds(
        (const __attribute__((address_space(1))) void*)(Bt + (n0+row)*(size_t)K + k0 + ke),
        (__attribute__((address_space(3))) void*)((char*)Bs + flat), 16, 0, 0);
    }
    asm volatile("s_waitcnt vmcnt(0)" ::: "memory");
    __syncthreads();

    short8 af[4], bf[4];
    #pragma unroll
    for(int mi=0;mi<4;mi++)
      af[mi] = *(const short8*)((const char*)As + (wr*64+mi*16+l16)*64 + l4*16);
    #pragma unroll
    for(int ni=0;ni<4;ni++)
      bf[ni] = *(const short8*)((const char*)Bs + (wc*64+ni*16+l16)*64 + l4*16);
    #pragma unroll
    for(int mi=0;mi<4;mi++)
      #pragma unroll
      for(int ni=0;ni<4;ni++)
        acc[mi][ni] = __builtin_amdgcn_mfma_f32_16x16x32_bf16(af[mi], bf[ni], acc[mi][ni], 0,0,0);
    __syncthreads();
  }

  #pragma unroll
  for(int ni=0;ni<4;ni++){
    const int col = (int)n0 + wc*64 + ni*16 + l16;
    const float bv = bias[col];
    #pragma unroll
    for(int mi=0;mi<4;mi++){
      #pragma unroll
      for(int r=0;r<4;r++){
        const int row = (int)m0 + wr*64 + mi*16 + l4*4 + r;
        float v = acc[mi][ni][r] + bv;
        if(relu) v = fmaxf(v, 0.f);
        size_t addr;
        if(xg_layout){
          const int tl = row >> 8, brow = row & 255;
          const int gg = brow >> 5, r32 = brow & 31;
          const int gate = col >> 9, cw = col & 511, ds2 = cw >> 4, c16 = cw & 15;
          addr = ((((size_t)tl*32 + ds2)*8 + gg)*3 + gate)*512 + r32*16 + c16;
        } else {
          addr = (size_t)row*N + col;
        }
        C[addr] = f2b(v);
      }
    }
  }
}

// ======================= cooperative GRU scan =======================
// 256 blocks x 128 thr. block = (g = bid>>5: 32 batch rows, ds = bid&31: 16 d-cols).
// Operand-swapped MFMA: D[d_out, batch] so each thread owns 1 row x 4 contiguous d.
// Flag-based group barrier (per-block flags, 128B apart, parallel poll).
__device__ __forceinline__ void flag_barrier(int* cntbase, int g, int ds, int target,
                                             int tid){
  asm volatile("s_waitcnt vmcnt(0)" ::: "memory");
  __syncthreads();
  if(tid == 0)
    __hip_atomic_store(cntbase + ((g<<5)+ds)*32, target,
                       __ATOMIC_RELAXED, __HIP_MEMORY_SCOPE_AGENT);
  if(tid < 32){
    const int* fp = cntbase + ((g<<5)+tid)*32;
    while(__hip_atomic_load(fp, __ATOMIC_RELAXED, __HIP_MEMORY_SCOPE_AGENT) < target)
      __builtin_amdgcn_s_sleep(1);
  }
  __syncthreads();
}

#define ALD(v, off) asm volatile("global_load_dwordx4 %0, %1, off offset:" off " sc0 sc1" \
                                 : "=&v"(v) : "v"(abase))

__global__ __launch_bounds__(128, 1) void k_scan_coop(
    const ushort* __restrict__ xg,        // scan-native layout, chunk-local
    const void* __restrict__ donep,
    const int* __restrict__ flagp, const float* __restrict__ h_in,
    const ushort* __restrict__ WhT, const float* __restrict__ bhn,
    ushort* __restrict__ ys, float* __restrict__ h_io,
    float* __restrict__ h_last, ushort* __restrict__ hbf,   // [2][256][512] bf16
    int t0, int steps, int* __restrict__ cntbase){
  __shared__ __align__(16) ushort whs[48*512];     // 48 KB
  __shared__ __align__(16) ushort xgs[2][1536];    // 6 KB double-buffered xg slice
  __shared__ unsigned char dns[512*32];            // 16 KB done bits for this group
  const int tid = threadIdx.x;
  const int m = tid >> 6, l = tid & 63, l16 = l & 15, l4 = l >> 4;
  const int bid = blockIdx.x;
  const int g = bid >> 5, ds = bid & 31;
  const int use8 = *flagp;
  const unsigned char* d8 = (const unsigned char*)donep;
  const int* d32 = (const int*)donep;

  // ---- stage WhT slice into LDS, swizzled ----
  for(int e = tid; e < 3072; e += 128){
    const int lr = e >> 6;              // local row 0..47 (gate*16 + d-within-16)
    const int kc = (e & 63) << 3;       // k 0..504 step 8
    const int grow_w = (lr >> 4)*DD + ds*16 + (lr & 15);
    short8 v = *(const short8*)(WhT + (size_t)grow_w*DD + kc);
    int boff = ((lr << 10) + (kc << 1)) ^ ((lr & 7) << 4);
    *(short8*)((char*)whs + boff) = v;
  }
  // ---- stage done bits for this group's 32 rows x steps ----
  for(int e = tid; e < steps*32; e += 128){
    const int tloc = e >> 5, r = e & 31;
    const int gi = (t0 + tloc)*BB + g*32 + r;
    dns[e] = use8 ? (d8[gi] != 0) : (d32[gi] != 0);
  }

  // ---- thread ownership: 1 batch row x 4 consecutive d ----
  const int row = g*32 + m*16 + l16;    // batch row (D-col side)
  const int d0  = ds*16 + l4*4;         // first of 4 d outputs (D-row side)
  const float4 bh4 = *(const float4*)(bhn + d0);

  // ---- prologue: load h f32, publish bf16 into hbf[0] (coherent 8B store) ----
  float hf[4];
  {
    const float4 hv4 = *(const float4*)(h_in + (size_t)row*DD + d0);
    hf[0]=hv4.x; hf[1]=hv4.y; hf[2]=hv4.z; hf[3]=hv4.w;
    union{ ushort u[4]; uint2 v; } p;
    #pragma unroll
    for(int r=0;r<4;r++) p.u[r] = f2b(hf[r]);
    const ushort* pp = hbf + (size_t)row*DD + d0;
    asm volatile("global_store_dwordx2 %0, %1, off sc0 sc1" :: "v"(pp), "v"(p.v) : "memory");
  }
  // ---- stage xg slice for step 0 into xgs[0] ----
  {
    const ushort* sl = xg + (((size_t)0*32 + ds)*8 + g)*1536;
    __builtin_amdgcn_global_load_lds(
      (const __attribute__((address_space(1))) void*)(sl + m*512 + l*8),
      (__attribute__((address_space(3))) void*)(&xgs[0][m*512]), 16, 0, 0);
    if(m == 0)
      __builtin_amdgcn_global_load_lds(
        (const __attribute__((address_space(1))) void*)(sl + 1024 + l*8),
        (__attribute__((address_space(3))) void*)(&xgs[0][1024]), 16, 0, 0);
  }
  flag_barrier(cntbase, g, ds, 1, tid);

  // wh-frag swizzle bases (gate gi -> local row gi*16 + l16)
  int rb[3], sw[3];
  #pragma unroll
  for(int gi=0; gi<3; gi++){
    const int lr = gi*16 + l16;
    rb[gi] = lr << 10;
    sw[gi] = (lr & 7) << 4;
  }
  const ushort* hb0 = hbf;
  const ushort* hb1 = hbf + (size_t)BB*DD;
  int cur = 0;

  for(int tl = 0; tl < steps; tl++){
    const ushort* hcur = (tl & 1) ? hb1 : hb0;
    ushort* hnxt = (ushort*)((tl & 1) ? hb0 : hb1);
    const bool dn = dns[tl*32 + (m*16 + l16)];   // this thread's row done?

    // ---- h-fragments (B operand): 16x dwordx4 sc0 sc1 ----
    const ushort* abase = hcur + (size_t)row*DD + l4*8;
    short8 a0,a1,a2,a3,a4,a5,a6,a7,a8,a9,a10,a11,a12,a13,a14,a15;
    ALD(a0,"0");    ALD(a1,"64");   ALD(a2,"128");  ALD(a3,"192");
    ALD(a4,"256");  ALD(a5,"320");  ALD(a6,"384");  ALD(a7,"448");
    ALD(a8,"512");  ALD(a9,"576");  ALD(a10,"640"); ALD(a11,"704");
    ALD(a12,"768"); ALD(a13,"832"); ALD(a14,"896"); ALD(a15,"960");
    asm volatile("s_waitcnt vmcnt(0)" ::: "memory");
    __builtin_amdgcn_sched_barrier(0);

    if(__builtin_expect(dn, 0)){
      const short8 z = {0,0,0,0,0,0,0,0};
      a0=z;a1=z;a2=z;a3=z;a4=z;a5=z;a6=z;a7=z;
      a8=z;a9=z;a10=z;a11=z;a12=z;a13=z;a14=z;a15=z;
    }

    // ---- prefetch next step's xg slice ----
    if(tl + 1 < steps){
      const int nb = cur ^ 1;
      const ushort* sl = xg + (((size_t)(tl+1)*32 + ds)*8 + g)*1536;
      __builtin_amdgcn_global_load_lds(
        (const __attribute__((address_space(1))) void*)(sl + m*512 + l*8),
        (__attribute__((address_space(3))) void*)(&xgs[nb][m*512]), 16, 0, 0);
      if(m == 0)
        __builtin_amdgcn_global_load_lds(
          (const __attribute__((address_space(1))) void*)(sl + 1024 + l*8),
          (__attribute__((address_space(3))) void*)(&xgs[nb][1024]), 16, 0, 0);
    }

    // ---- 48 MFMA: operand-swapped mfma(Wh, h) -> D[d_out, batch] ----
    f32x4 acc[3] = {};
    #define STEPK(ak, k0lit) { \
      const int kboff = ((k0lit + l4*8) << 1); \
      _Pragma("unroll") \
      for(int gi=0; gi<3; gi++){ \
        const short8 wf = *(const short8*)((const char*)whs + ((rb[gi] + kboff) ^ sw[gi])); \
        acc[gi] = __builtin_amdgcn_mfma_f32_16x16x32_bf16(wf, ak, acc[gi], 0, 0, 0); \
      } }
    STEPK(a0,0)    STEPK(a1,32)   STEPK(a2,64)   STEPK(a3,96)
    STEPK(a4,128)  STEPK(a5,160)  STEPK(a6,192)  STEPK(a7,224)
    STEPK(a8,256)  STEPK(a9,288)  STEPK(a10,320) STEPK(a11,352)
    STEPK(a12,384) STEPK(a13,416) STEPK(a14,448) STEPK(a15,480)
    #undef STEPK

    // ---- epilogue: this thread = 1 row x 4 consecutive d ----
    {
      const int r32 = m*16 + l16;
      const uint2 xru = *(const uint2*)&xgs[cur][        r32*16 + l4*4];
      const uint2 xzu = *(const uint2*)&xgs[cur][ 512 +  r32*16 + l4*4];
      const uint2 xnu = *(const uint2*)&xgs[cur][1024 +  r32*16 + l4*4];
      const ushort xr4[4] = {(ushort)(xru.x&0xffff),(ushort)(xru.x>>16),
                             (ushort)(xru.y&0xffff),(ushort)(xru.y>>16)};
      const ushort xz4[4] = {(ushort)(xzu.x&0xffff),(ushort)(xzu.x>>16),
                             (ushort)(xzu.y&0xffff),(ushort)(xzu.y>>16)};
      const ushort xn4[4] = {(ushort)(xnu.x&0xffff),(ushort)(xnu.x>>16),
                             (ushort)(xnu.y&0xffff),(ushort)(xnu.y>>16)};
      const float bhv[4] = {bh4.x, bh4.y, bh4.z, bh4.w};
      union{ ushort u[4]; uint2 v; } p;
      #pragma unroll
      for(int r=0;r<4;r++){
        const float hold = dn ? 0.f : hf[r];
        const float rg = sigm(b2f(xr4[r]) + acc[0][r]);
        const float zg = sigm(b2f(xz4[r]) + acc[1][r]);
        const float ng = tanh_f(b2f(xn4[r]) + rg*(acc[2][r] + bhv[r]));
        const float hv = (1.f - zg)*ng + zg*hold;
        hf[r] = hv;
        p.u[r] = f2b(hv);
      }
      const ushort* pp = hnxt + (size_t)row*DD + d0;
      asm volatile("global_store_dwordx2 %0, %1, off sc0 sc1" :: "v"(pp), "v"(p.v) : "memory");
      *(uint2*)(ys + ((size_t)tl*BB + row)*DD + d0) = p.v;
    }
    flag_barrier(cntbase, g, ds, tl + 2, tid);
    cur ^= 1;
  }

  {
    float4 o; o.x=hf[0]; o.y=hf[1]; o.z=hf[2]; o.w=hf[3];
    *(float4*)(h_io   + (size_t)row*DD + d0) = o;
    *(float4*)(h_last + (size_t)row*DD + d0) = o;
  }
}

// ---------------- fallback GRU scan (16 blocks; scan-native xg layout) ----------------
__global__ __launch_bounds__(1024) void k_scan(const ushort* __restrict__ xg,
                                               const void* __restrict__ donep,
                                               const int* __restrict__ flagp,
                                               const float* __restrict__ h_in,
                                               const ushort* __restrict__ WhT,
                                               const float* __restrict__ bhn,
                                               ushort* __restrict__ ys,
                                               float* __restrict__ h_io,
                                               float* __restrict__ h_last,
                                               int t0, int steps){
  __shared__ __align__(16) float  h_f[16][DD];
  __shared__ __align__(16) ushort h_b[16][DD];
  const int tid = threadIdx.x;
  const int w = tid >> 6, l = tid & 63, l16 = l & 15, l4 = l >> 4;
  const int b0 = blockIdx.x * 16;
  const int use8 = *flagp;
  const unsigned char* d8 = (const unsigned char*)donep;
  const int* d32 = (const int*)donep;

  for(int e = tid; e < 16*DD; e += 1024){
    int b = e >> 9, dd = e & (DD-1);
    float v = h_in[(size_t)(b0 + b)*DD + dd];
    h_f[b][dd] = v; h_b[b][dd] = f2b(v);
  }
  __syncthreads();

  const int dbase = w * 32;
  const ushort* bp[6];
  #pragma unroll
  for(int g=0; g<3; g++)
    #pragma unroll
    for(int nt=0; nt<2; nt++)
      bp[g*2+nt] = WhT + (size_t)(g*DD + dbase + nt*16 + l16) * DD;

  for(int tl = 0; tl < steps; tl++){
    const int drow = (t0 + tl)*BB + b0;
    const bool dnA = use8 ? (d8[drow + l16] != 0) : (d32[drow + l16] != 0);
    f32x4 acc[3][2] = {};
    const short8 zf = {0,0,0,0,0,0,0,0};
    for(int k0 = 0; k0 < DD; k0 += 32){
      const int kb = k0 + l4*8;
      short8 a = *(const short8*)&h_b[l16][kb];
      if(dnA) a = zf;
      #pragma unroll
      for(int g=0; g<3; g++)
        #pragma unroll
        for(int nt=0; nt<2; nt++){
          const short8 b = *(const short8*)(bp[g*2+nt] + kb);
          acc[g][nt] = __builtin_amdgcn_mfma_f32_16x16x32_bf16(a, b, acc[g][nt], 0, 0, 0);
        }
    }
    float hnew[2][4];
    #pragma unroll
    for(int nt=0; nt<2; nt++){
      const int dd = dbase + nt*16 + l16;
      const float bh = bhn[dd];
      const int ds2 = dd >> 4, c16 = dd & 15;
      #pragma unroll
      for(int r=0; r<4; r++){
        const int brow = l4*4 + r;
        const int grow = b0 + brow;
        const int gg = grow >> 5, r32 = grow & 31;
        const bool dn = use8 ? (d8[drow + brow] != 0) : (d32[drow + brow] != 0);
        const size_t sbase = (((size_t)tl*32 + ds2)*8 + gg)*1536 + r32*16 + c16;
        const float xr = b2f(xg[sbase]);
        const float xz = b2f(xg[sbase + 512]);
        const float xn = b2f(xg[sbase + 1024]);
        const float hold = dn ? 0.f : h_f[brow][dd];
        const float rg = sigm(xr + acc[0][nt][r]);
        const float zg = sigm(xz + acc[1][nt][r]);
        const float ng = tanh_f(xn + rg*(acc[2][nt][r] + bh));
        hnew[nt][r] = (1.f - zg)*ng + zg*hold;
      }
    }
    __syncthreads();
    #pragma unroll
    for(int nt=0; nt<2; nt++){
      const int dd = dbase + nt*16 + l16;
      #pragma unroll
      for(int r=0; r<4; r++){
        const int brow = l4*4 + r;
        const size_t rowl = (size_t)(tl*BB + b0 + brow);
        const float hv = hnew[nt][r];
        h_f[brow][dd] = hv;
        h_b[brow][dd] = f2b(hv);
        ys[rowl*DD + dd] = f2b(hv);
      }
    }
    __syncthreads();
  }

  for(int e = tid; e < 16*DD; e += 1024){
    int b = e >> 9, dd = e & (DD-1);
    float v = h_f[b][dd];
    h_io[(size_t)(b0 + b)*DD + dd] = v;
    h_last[(size_t)(b0 + b)*DD + dd] = v;
  }
}

// ---------------- value GEMV ----------------
__global__ __launch_bounds__(256) void k_value(const ushort* __restrict__ critic,
                                               const float* __restrict__ W2,
                                               const float* __restrict__ b2,
                                               float* __restrict__ val){
  const int w = threadIdx.x >> 6, l = threadIdx.x & 63;
  const size_t row = (size_t)blockIdx.x*4 + w;
  const ushort* cp = critic + row*HH + l*8;
  const float* wp = W2 + l*8;
  float s = 0.f;
  #pragma unroll
  for(int j=0;j<8;j++) s += b2f(cp[j]) * wp[j];
  for(int off=32; off; off>>=1) s += __shfl_down(s, off, 64);
  if(l == 0) val[row] = s + b2[0];
}

extern "C" void kernel_launch(void* const* d_in, const int* in_sizes, int n_in,
                              void* d_out, int out_size, void* d_ws, size_t ws_size,
                              hipStream_t stream){
  const float* obs    = (const float*)d_in[0];
  const void*  done   = d_in[1];
  const float* hstate = (const float*)d_in[2];
  const float* W_emb  = (const float*)d_in[3];
  const float* b_emb  = (const float*)d_in[4];
  const float* Wi     = (const float*)d_in[5];
  const float* bi     = (const float*)d_in[6];
  const float* Wh     = (const float*)d_in[7];
  const float* bhn    = (const float*)d_in[8];
  const float* W1     = (const float*)d_in[9];
  const float* b1     = (const float*)d_in[10];
  const float* W2     = (const float*)d_in[11];
  const float* b2     = (const float*)d_in[12];
  float* out = (float*)d_out;
  char*  ws  = (char*)d_ws;

  // ---- fixed ws region ----
  ushort* WembT = (ushort*)(ws + 0);           // 262144
  ushort* WiT   = (ushort*)(ws + 262144);      // -> 1835008
  ushort* WhT   = (ushort*)(ws + 1835008);     // -> 3407872
  ushort* W1T   = (ushort*)(ws + 3407872);     // -> 3932160
  int*    flag  = (int*)   (ws + 3932160);     // 4
  float*  hio   = (float*) (ws + 3936256);     // -> 4460544
  ushort* hbf   = (ushort*)(ws + 4460544);     // 2*256*512*2 = 524288 -> 4984832
  int*    cnt   = (int*)   (ws + 4984832);     // 256 flags * 128B = 32768 -> 5017600
  const size_t FIX = 5242880;                  // 5 MiB

  int TC = 0;
  {
    const int cands[6] = {512, 256, 128, 64, 32, 16};
    for(int i = 0; i < 6; i++){
      size_t need = FIX + (size_t)cands[i] * 1310720u;
      if(need <= ws_size){ TC = cands[i]; break; }
    }
  }
  if(TC == 0) return;

  ushort* emb_c  = (ushort*)(ws + FIX);
  ushort* xg_c   = (ushort*)(ws + FIX + (size_t)TC*262144u);
  ushort* ys_c   = (ushort*)(ws + FIX + (size_t)TC*1048576u);
  ushort* crit_c = emb_c;
  ushort* obs_bf = ys_c;   // obs_bf (TC*131072 B) overlaps ys (TC*262144 B): dead before scan

  k_transpose_bf16<<<(OBSD*DD+255)/256, 256, 0, stream>>>(W_emb, WembT, OBSD, DD);
  k_transpose_bf16<<<(DD*3*DD+255)/256, 256, 0, stream>>>(Wi, WiT, DD, 3*DD);
  k_transpose_bf16<<<(DD*3*DD+255)/256, 256, 0, stream>>>(Wh, WhT, DD, 3*DD);
  k_transpose_bf16<<<(DD*HH+255)/256, 256, 0, stream>>>(W1, W1T, DD, HH);
  k_detect<<<1, 256, 0, stream>>>((const int*)done, flag);

  const int nchunks = TT / TC;
  for(int c = 0; c < nchunks; c++){
    const int Mc = TC * BB;
    const size_t row0 = (size_t)c * Mc;
    // obs chunk -> bf16
    k_f32_to_bf16<<<(Mc*OBSD/4 + 255)/256, 256, 0, stream>>>(obs + row0*OBSD, obs_bf,
                                                             Mc*OBSD/4);
    // emb = relu(obs @ W_emb + b_emb)
    k_gemm128<<<dim3(Mc/128, DD/128), 256, 0, stream>>>(obs_bf, WembT, b_emb,
                                                        emb_c, Mc, DD, OBSD, 1, 0);
    // xg = emb @ Wi + bi  (scan-native layout)
    k_gemm128<<<dim3(Mc/128, (3*DD)/128), 256, 0, stream>>>(emb_c, WiT, bi,
                                                            xg_c, Mc, 3*DD, DD, 0, 1);
    {
      const ushort* xg_a = xg_c;  const void* done_a = done;
      const int* flag_a = flag;   const float* hin_a = (c == 0) ? hstate : hio;
      const ushort* wht_a = WhT;  const float* bhn_a = bhn;
      ushort* ys_a = ys_c;        float* hio_a = hio;
      float* hl_a = out;          ushort* hbf_a = hbf;
      int t0_a = c*TC;            int steps_a = TC;
      int* cnt_a = cnt;
      void* args[13] = { (void*)&xg_a, (void*)&done_a, (void*)&flag_a, (void*)&hin_a,
                         (void*)&wht_a, (void*)&bhn_a, (void*)&ys_a, (void*)&hio_a,
                         (void*)&hl_a, (void*)&hbf_a, (void*)&t0_a, (void*)&steps_a,
                         (void*)&cnt_a };
      hipMemsetAsync(cnt, 0, 32768, stream);
      hipError_t err = hipLaunchCooperativeKernel((const void*)k_scan_coop,
                                                  dim3(256), dim3(128), args, 0, stream);
      if(err != hipSuccess){
        k_scan<<<16, 1024, 0, stream>>>(xg_c, done, flag, hin_a, WhT, bhn,
                                        ys_c, hio, out, c*TC, TC);
      }
    }
    // critic = relu(ys @ W1 + b1)
    k_gemm128<<<dim3(Mc/128, HH/128), 256, 0, stream>>>(ys_c, W1T, b1,
                                                        crit_c, Mc, HH, DD, 1, 0);
    // value = critic @ W2 + b2
    k_value<<<Mc/4, 256, 0, stream>>>(crit_c, W2, b2, out + (size_t)BB*DD + row0);
  }
}